// Round 2
// baseline (318.019 us; speedup 1.0000x reference)
//
#include <hip/hip_runtime.h>

typedef _Float16 f16x8 __attribute__((ext_vector_type(8)));
typedef float f32x4 __attribute__((ext_vector_type(4)));

#define NMAT3 (3 * 768 * 64)

// ---------------- Kernel 0: W transpose/convert ----------------
// Wt layout: [n = mat*64 + d][k = 0..767], f16.  n rows of 768 contiguous.
__global__ __launch_bounds__(256) void prep_w(const float* __restrict__ Wq,
                                              const float* __restrict__ Wk,
                                              const float* __restrict__ Wv,
                                              _Float16* __restrict__ wt) {
    int tid = blockIdx.x * 256 + threadIdx.x;
    if (tid >= NMAT3) return;
    int m = tid / (768 * 64);
    int rem = tid - m * (768 * 64);
    int k = rem >> 6;
    int n = rem & 63;
    const float* W = (m == 0) ? Wq : (m == 1) ? Wk : Wv;
    float v = W[k * 64 + n];           // coalesced read over n
    wt[(m * 64 + n) * 768 + k] = (_Float16)v;  // transposed write (tiny, L2)
}

// ---------------- Kernel 1: fused QKV projection ----------------
// Block: 256 thr (4 waves). Tile: 64 rows x 192 cols (q|k|v). K-loop step 32.
__global__ __launch_bounds__(256) void qkv_proj(const float* __restrict__ x,
                                                const _Float16* __restrict__ wt,
                                                const float* __restrict__ bq,
                                                const float* __restrict__ bk,
                                                const float* __restrict__ bv,
                                                _Float16* __restrict__ qo,
                                                _Float16* __restrict__ ko,
                                                _Float16* __restrict__ vo) {
    __shared__ alignas(16) _Float16 xs[64][40];    // 64 rows x 32 k, pad->40
    __shared__ alignas(16) _Float16 wsh[192][40];  // 192 n  x 32 k, pad->40

    const int t = threadIdx.x;
    const int lane = t & 63;
    const int w = t >> 6;
    const int l15 = lane & 15;
    const int lg = lane >> 4;
    const int rbase = blockIdx.x * 64;

    f32x4 acc[12];
#pragma unroll
    for (int i = 0; i < 12; i++) acc[i] = (f32x4)(0.0f);

    for (int k0 = 0; k0 < 768; k0 += 32) {
        __syncthreads();  // protect previous iteration's LDS reads
        {   // stage x tile (fp32 -> f16)
            int row = t >> 2;
            int c8 = (t & 3) * 8;
            const float* src = x + (rbase + row) * 768 + k0 + c8;
            float4 a0 = *(const float4*)(src);
            float4 a1 = *(const float4*)(src + 4);
            f16x8 h;
            h[0] = (_Float16)a0.x; h[1] = (_Float16)a0.y;
            h[2] = (_Float16)a0.z; h[3] = (_Float16)a0.w;
            h[4] = (_Float16)a1.x; h[5] = (_Float16)a1.y;
            h[6] = (_Float16)a1.z; h[7] = (_Float16)a1.w;
            *(f16x8*)(&xs[row][c8]) = h;
        }
#pragma unroll
        for (int j = 0; j < 3; j++) {  // stage Wt slab: 192 rows x 4 chunks
            int e = t + 256 * j;
            int n = e >> 2;
            int c = (e & 3) * 8;
            f16x8 s = *(const f16x8*)(wt + n * 768 + k0 + c);
            *(f16x8*)(&wsh[n][c]) = s;
        }
        __syncthreads();

        f16x8 afrag = *(const f16x8*)(&xs[16 * w + l15][lg * 8]);
#pragma unroll
        for (int bf = 0; bf < 12; bf++) {
            f16x8 bfrag = *(const f16x8*)(&wsh[16 * bf + l15][lg * 8]);
            acc[bf] = __builtin_amdgcn_mfma_f32_16x16x32_f16(afrag, bfrag, acc[bf], 0, 0, 0);
        }
    }

    _Float16* outs[3] = {qo, ko, vo};
    const float* biases[3] = {bq, bk, bv};
#pragma unroll
    for (int bf = 0; bf < 12; bf++) {
        const int mat = bf >> 2;
        const int dcol = (bf & 3) * 16 + l15;
        const float bias = biases[mat][dcol];
#pragma unroll
        for (int r = 0; r < 4; r++) {
            int grow = rbase + 16 * w + lg * 4 + r;
            outs[mat][grow * 64 + dcol] = (_Float16)(acc[bf][r] + bias);
        }
    }
}

// ---------------- Kernel 2: causal flash attention ----------------
// Block: 256 thr (4 waves), QBLK=64 (16 q-rows/wave), SBLK=64.
__global__ __launch_bounds__(256) void attn(const _Float16* __restrict__ qg,
                                            const _Float16* __restrict__ kg,
                                            const _Float16* __restrict__ vg,
                                            float* __restrict__ out) {
    __shared__ alignas(16) _Float16 Ks[64][72];      // [s][d], pad 64->72
    __shared__ alignas(16) _Float16 Vs[64][72];      // [d][s] (transposed)
    __shared__ alignas(16) _Float16 Ps[4][16][72];   // per-wave P tile

    const int t = threadIdx.x;
    const int lane = t & 63;
    const int w = t >> 6;
    const int l15 = lane & 15;
    const int lg = lane >> 4;

    const int bid = blockIdx.x;
    const int b = bid >> 6;
    const int qt = 63 - (bid & 63);     // heavy q-tiles dispatched first
    const int qbase = qt * 64;
    const long rowb = (long)b * 4096;

    f16x8 qf[2];
    {
        const _Float16* qptr = qg + (rowb + qbase + 16 * w + l15) * 64 + lg * 8;
        qf[0] = *(const f16x8*)(qptr);
        qf[1] = *(const f16x8*)(qptr + 32);
    }

    f32x4 oacc[4];
#pragma unroll
    for (int i = 0; i < 4; i++) oacc[i] = (f32x4)(0.0f);
    float mrow[4], lrow[4];
#pragma unroll
    for (int r = 0; r < 4; r++) { mrow[r] = -1e30f; lrow[r] = 0.0f; }

    const float kscale = 0.125f * 1.44269504088896340736f;  // 1/sqrt(64) * log2(e)

    for (int st = 0; st <= qt; st++) {
        const int sbase = st * 64;
        __syncthreads();
        {   // stage K tile row-major
            int s = t >> 2;
            int d0 = (t & 3) * 16;
            const _Float16* src = kg + (rowb + sbase + s) * 64 + d0;
            f16x8 k0v = *(const f16x8*)(src);
            f16x8 k1v = *(const f16x8*)(src + 8);
            *(f16x8*)(&Ks[s][d0]) = k0v;
            *(f16x8*)(&Ks[s][d0 + 8]) = k1v;
        }
        {   // stage V transposed: Vs[d][s]
            int s = t & 63;
            int d0 = (t >> 6) * 16;
            const _Float16* src = vg + (rowb + sbase + s) * 64 + d0;
            f16x8 v0 = *(const f16x8*)(src);
            f16x8 v1 = *(const f16x8*)(src + 8);
#pragma unroll
            for (int j = 0; j < 8; j++) Vs[d0 + j][s] = v0[j];
#pragma unroll
            for (int j = 0; j < 8; j++) Vs[d0 + 8 + j][s] = v1[j];
        }
        __syncthreads();

        // S = Q K^T  (wave computes its 16 q-rows x 64 s-cols)
        f32x4 sacc[4];
#pragma unroll
        for (int cf = 0; cf < 4; cf++) {
            sacc[cf] = (f32x4)(0.0f);
#pragma unroll
            for (int kk = 0; kk < 2; kk++) {
                f16x8 bfrag = *(const f16x8*)(&Ks[16 * cf + l15][kk * 32 + lg * 8]);
                sacc[cf] = __builtin_amdgcn_mfma_f32_16x16x32_f16(qf[kk], bfrag, sacc[cf], 0, 0, 0);
            }
        }

        // scale + causal mask (only the diagonal tile needs masking)
        const bool diag = (st == qt);
        float sv[4][4];
#pragma unroll
        for (int cf = 0; cf < 4; cf++) {
            int scol = sbase + 16 * cf + l15;
#pragma unroll
            for (int r = 0; r < 4; r++) {
                float val = sacc[cf][r] * kscale;
                if (diag) {
                    int qrow = qbase + 16 * w + lg * 4 + r;
                    if (scol > qrow) val = -1e30f;
                }
                sv[cf][r] = val;
            }
        }

        // online softmax: wave-parallel 16-wide reductions (all 64 lanes busy)
        float fr[4];
#pragma unroll
        for (int r = 0; r < 4; r++) {
            float mx = fmaxf(fmaxf(sv[0][r], sv[1][r]), fmaxf(sv[2][r], sv[3][r]));
            mx = fmaxf(mx, __shfl_xor(mx, 1, 64));
            mx = fmaxf(mx, __shfl_xor(mx, 2, 64));
            mx = fmaxf(mx, __shfl_xor(mx, 4, 64));
            mx = fmaxf(mx, __shfl_xor(mx, 8, 64));
            float mnew = fmaxf(mrow[r], mx);
            fr[r] = __builtin_amdgcn_exp2f(mrow[r] - mnew);
            mrow[r] = mnew;
            float psum = 0.0f;
#pragma unroll
            for (int cf = 0; cf < 4; cf++) {
                float p = __builtin_amdgcn_exp2f(sv[cf][r] - mnew);
                sv[cf][r] = p;
                psum += p;
            }
            psum += __shfl_xor(psum, 1, 64);
            psum += __shfl_xor(psum, 2, 64);
            psum += __shfl_xor(psum, 4, 64);
            psum += __shfl_xor(psum, 8, 64);
            lrow[r] = lrow[r] * fr[r] + psum;
        }
#pragma unroll
        for (int df = 0; df < 4; df++)
#pragma unroll
            for (int r = 0; r < 4; r++) oacc[df][r] *= fr[r];

        // P -> LDS (re-layout D-frag -> A-frag), per-wave buffer, no barrier
#pragma unroll
        for (int cf = 0; cf < 4; cf++)
#pragma unroll
            for (int r = 0; r < 4; r++)
                Ps[w][lg * 4 + r][16 * cf + l15] = (_Float16)sv[cf][r];

        // O += P V
#pragma unroll
        for (int kk = 0; kk < 2; kk++) {
            f16x8 pfrag = *(const f16x8*)(&Ps[w][l15][kk * 32 + lg * 8]);
#pragma unroll
            for (int df = 0; df < 4; df++) {
                f16x8 vfrag = *(const f16x8*)(&Vs[16 * df + l15][kk * 32 + lg * 8]);
                oacc[df] = __builtin_amdgcn_mfma_f32_16x16x32_f16(pfrag, vfrag, oacc[df], 0, 0, 0);
            }
        }
    }

    // epilogue: normalize and store fp32
#pragma unroll
    for (int df = 0; df < 4; df++) {
#pragma unroll
        for (int r = 0; r < 4; r++) {
            int qrow = qbase + 16 * w + lg * 4 + r;
            out[(rowb + qrow) * 64 + 16 * df + l15] = oacc[df][r] / lrow[r];
        }
    }
}

extern "C" void kernel_launch(void* const* d_in, const int* in_sizes, int n_in,
                              void* d_out, int out_size, void* d_ws, size_t ws_size,
                              hipStream_t stream) {
    const float* x  = (const float*)d_in[0];
    const float* Wq = (const float*)d_in[1];
    const float* bq = (const float*)d_in[2];
    const float* Wk = (const float*)d_in[3];
    const float* bk = (const float*)d_in[4];
    const float* Wv = (const float*)d_in[5];
    const float* bv = (const float*)d_in[6];
    float* out = (float*)d_out;

    _Float16* ws = (_Float16*)d_ws;
    _Float16* wt = ws;                       // 3*64*768
    _Float16* qb = ws + 147456;              // 32768*64
    _Float16* kb = qb + 2097152;
    _Float16* vb = kb + 2097152;

    prep_w<<<576, 256, 0, stream>>>(Wq, Wk, Wv, wt);
    qkv_proj<<<512, 256, 0, stream>>>(x, wt, bq, bk, bv, qb, kb, vb);
    attn<<<512, 256, 0, stream>>>(qb, kb, vb, out);
}

// Round 3
// 306.067 us; speedup vs baseline: 1.0390x; 1.0390x over previous
//
#include <hip/hip_runtime.h>

typedef _Float16 f16x8 __attribute__((ext_vector_type(8)));
typedef float f32x4 __attribute__((ext_vector_type(4)));

#define NMAT3 (3 * 768 * 64)

// ---------------- Kernel 0: W transpose/convert ----------------
// Wt layout: [n = mat*64 + d][k = 0..767], f16.
__global__ __launch_bounds__(256) void prep_w(const float* __restrict__ Wq,
                                              const float* __restrict__ Wk,
                                              const float* __restrict__ Wv,
                                              _Float16* __restrict__ wt) {
    int tid = blockIdx.x * 256 + threadIdx.x;
    if (tid >= NMAT3) return;
    int m = tid / (768 * 64);
    int rem = tid - m * (768 * 64);
    int k = rem >> 6;
    int n = rem & 63;
    const float* W = (m == 0) ? Wq : (m == 1) ? Wk : Wv;
    float v = W[k * 64 + n];
    wt[(m * 64 + n) * 768 + k] = (_Float16)v;
}

// ---------------- Kernel 1: fused QKV projection (LDS-free, barrier-free) --
// 4 waves/block, each wave owns 16 rows x 192 cols. A from x (fp32->f16),
// B fragments straight from wt (L2-resident). No __syncthreads at all.
__global__ __launch_bounds__(256) void qkv_proj(const float* __restrict__ x,
                                                const _Float16* __restrict__ wt,
                                                const float* __restrict__ bq,
                                                const float* __restrict__ bk,
                                                const float* __restrict__ bv,
                                                _Float16* __restrict__ qo,
                                                _Float16* __restrict__ ko,
                                                _Float16* __restrict__ vo) {
    const int t = threadIdx.x;
    const int lane = t & 63;
    const int w = t >> 6;
    const int l15 = lane & 15;
    const int lg = lane >> 4;
    const int row0 = blockIdx.x * 64 + w * 16;   // wave's 16-row tile

    f32x4 acc[12];
#pragma unroll
    for (int i = 0; i < 12; i++) acc[i] = (f32x4)(0.0f);

    const float* xrow = x + (long)(row0 + l15) * 768;

    for (int k0 = 0; k0 < 768; k0 += 32) {
        const float* ap = xrow + k0 + lg * 8;
        float4 a0 = *(const float4*)(ap);
        float4 a1 = *(const float4*)(ap + 4);
        f16x8 af;
        af[0] = (_Float16)a0.x; af[1] = (_Float16)a0.y;
        af[2] = (_Float16)a0.z; af[3] = (_Float16)a0.w;
        af[4] = (_Float16)a1.x; af[5] = (_Float16)a1.y;
        af[6] = (_Float16)a1.z; af[7] = (_Float16)a1.w;
#pragma unroll
        for (int nf = 0; nf < 12; nf++) {
            f16x8 bf = *(const f16x8*)(wt + (long)(nf * 16 + l15) * 768 + k0 + lg * 8);
            acc[nf] = __builtin_amdgcn_mfma_f32_16x16x32_f16(af, bf, acc[nf], 0, 0, 0);
        }
    }

    _Float16* outs[3] = {qo, ko, vo};
    const float* biases[3] = {bq, bk, bv};
#pragma unroll
    for (int nf = 0; nf < 12; nf++) {
        const int mat = nf >> 2;
        const int dcol = (nf & 3) * 16 + l15;
        const float bias = biases[mat][dcol];
#pragma unroll
        for (int r = 0; r < 4; r++) {
            int grow = row0 + lg * 4 + r;
            outs[mat][(long)grow * 64 + dcol] = (_Float16)(acc[nf][r] + bias);
        }
    }
}

// ---------------- Kernel 2: causal flash attention ----------------
// 4 waves (QBLK=64, 16 q-rows/wave), SBLK=64, double-buffered K/V staging,
// loads for tile t+1 issued before compute on tile t, ONE barrier/iter.
__global__ __launch_bounds__(256) void attn(const _Float16* __restrict__ qg,
                                            const _Float16* __restrict__ kg,
                                            const _Float16* __restrict__ vg,
                                            float* __restrict__ out) {
    __shared__ alignas(16) _Float16 Ks[2][64][72];
    __shared__ alignas(16) _Float16 Vs[2][64][72];   // [d][s] transposed
    __shared__ alignas(16) _Float16 Ps[4][16][72];

    const int t = threadIdx.x;
    const int lane = t & 63;
    const int w = t >> 6;
    const int l15 = lane & 15;
    const int lg = lane >> 4;

    // Load-balanced qt mapping: blocks bid and bid+256 (same CU) have
    // complementary weights (qt sum = 63).
    const int bid = blockIdx.x;
    int b, qt;
    if (bid < 256) { b = bid >> 6;             qt = 63 - (bid & 63); }
    else           { b = 4 + ((bid - 256) >> 6); qt = bid & 63; }
    const int qbase = qt * 64;
    const long rowb = (long)b * 4096;

    // staging assignment: thread covers K row sK cols dK..dK+15 and same for V
    const int sK = lane;
    const int dK = w * 16;

    f16x8 qf[2];
    {
        const _Float16* qptr = qg + (rowb + qbase + 16 * w + l15) * 64 + lg * 8;
        qf[0] = *(const f16x8*)(qptr);
        qf[1] = *(const f16x8*)(qptr + 32);
    }

    f32x4 oacc[4];
#pragma unroll
    for (int i = 0; i < 4; i++) oacc[i] = (f32x4)(0.0f);
    float mrow[4], lrow[4];
#pragma unroll
    for (int r = 0; r < 4; r++) { mrow[r] = -1e30f; lrow[r] = 0.0f; }

    const float kscale = 0.125f * 1.44269504088896340736f;  // 1/sqrt(64)*log2(e)

    f16x8 krg0, krg1, vrg0, vrg1;
    // prologue: load tile 0 and store to buffer 0
    {
        const _Float16* ksrc = kg + (rowb + sK) * 64 + dK;
        krg0 = *(const f16x8*)(ksrc);
        krg1 = *(const f16x8*)(ksrc + 8);
        const _Float16* vsrc = vg + (rowb + sK) * 64 + dK;
        vrg0 = *(const f16x8*)(vsrc);
        vrg1 = *(const f16x8*)(vsrc + 8);
        *(f16x8*)(&Ks[0][sK][dK]) = krg0;
        *(f16x8*)(&Ks[0][sK][dK + 8]) = krg1;
#pragma unroll
        for (int j = 0; j < 8; j++) Vs[0][dK + j][sK] = vrg0[j];
#pragma unroll
        for (int j = 0; j < 8; j++) Vs[0][dK + 8 + j][sK] = vrg1[j];
    }

    for (int st = 0; st <= qt; st++) {
        const int cur = st & 1;
        const int sbase = st * 64;
        __syncthreads();   // buffer[cur] ready (covers prologue / prev write)

        // issue next tile's global loads early (latency hides under compute)
        if (st < qt) {
            const long nb = rowb + sbase + 64 + sK;
            const _Float16* ksrc = kg + nb * 64 + dK;
            krg0 = *(const f16x8*)(ksrc);
            krg1 = *(const f16x8*)(ksrc + 8);
            const _Float16* vsrc = vg + nb * 64 + dK;
            vrg0 = *(const f16x8*)(vsrc);
            vrg1 = *(const f16x8*)(vsrc + 8);
        }

        // S = Q K^T
        f32x4 sacc[4];
#pragma unroll
        for (int cf = 0; cf < 4; cf++) {
            sacc[cf] = (f32x4)(0.0f);
#pragma unroll
            for (int kk = 0; kk < 2; kk++) {
                f16x8 bfrag = *(const f16x8*)(&Ks[cur][16 * cf + l15][kk * 32 + lg * 8]);
                sacc[cf] = __builtin_amdgcn_mfma_f32_16x16x32_f16(qf[kk], bfrag, sacc[cf], 0, 0, 0);
            }
        }

        const bool diag = (st == qt);
        float sv[4][4];
#pragma unroll
        for (int cf = 0; cf < 4; cf++) {
            int scol = sbase + 16 * cf + l15;
#pragma unroll
            for (int r = 0; r < 4; r++) {
                float val = sacc[cf][r] * kscale;
                if (diag) {
                    int qrow = qbase + 16 * w + lg * 4 + r;
                    if (scol > qrow) val = -1e30f;
                }
                sv[cf][r] = val;
            }
        }

        // online softmax (16-wide shfl reductions; 4 r-chains interleave)
        float fr[4];
#pragma unroll
        for (int r = 0; r < 4; r++) {
            float mx = fmaxf(fmaxf(sv[0][r], sv[1][r]), fmaxf(sv[2][r], sv[3][r]));
            mx = fmaxf(mx, __shfl_xor(mx, 1, 64));
            mx = fmaxf(mx, __shfl_xor(mx, 2, 64));
            mx = fmaxf(mx, __shfl_xor(mx, 4, 64));
            mx = fmaxf(mx, __shfl_xor(mx, 8, 64));
            float mnew = fmaxf(mrow[r], mx);
            fr[r] = __builtin_amdgcn_exp2f(mrow[r] - mnew);
            mrow[r] = mnew;
            float psum = 0.0f;
#pragma unroll
            for (int cf = 0; cf < 4; cf++) {
                float p = __builtin_amdgcn_exp2f(sv[cf][r] - mnew);
                sv[cf][r] = p;
                psum += p;
            }
            psum += __shfl_xor(psum, 1, 64);
            psum += __shfl_xor(psum, 2, 64);
            psum += __shfl_xor(psum, 4, 64);
            psum += __shfl_xor(psum, 8, 64);
            lrow[r] = lrow[r] * fr[r] + psum;
        }
#pragma unroll
        for (int df = 0; df < 4; df++)
#pragma unroll
            for (int r = 0; r < 4; r++) oacc[df][r] *= fr[r];

        // P -> per-wave LDS (re-layout D-frag -> A-frag)
#pragma unroll
        for (int cf = 0; cf < 4; cf++)
#pragma unroll
            for (int r = 0; r < 4; r++)
                Ps[w][lg * 4 + r][16 * cf + l15] = (_Float16)sv[cf][r];

        // O += P V
#pragma unroll
        for (int kk = 0; kk < 2; kk++) {
            f16x8 pfrag = *(const f16x8*)(&Ps[w][l15][kk * 32 + lg * 8]);
#pragma unroll
            for (int df = 0; df < 4; df++) {
                f16x8 vfrag = *(const f16x8*)(&Vs[cur][16 * df + l15][kk * 32 + lg * 8]);
                oacc[df] = __builtin_amdgcn_mfma_f32_16x16x32_f16(pfrag, vfrag, oacc[df], 0, 0, 0);
            }
        }

        // stage next tile into the other buffer (no extra barrier needed:
        // writes target buf cur^1, all reads this iter were from buf cur)
        if (st < qt) {
            const int nxt = cur ^ 1;
            *(f16x8*)(&Ks[nxt][sK][dK]) = krg0;
            *(f16x8*)(&Ks[nxt][sK][dK + 8]) = krg1;
#pragma unroll
            for (int j = 0; j < 8; j++) Vs[nxt][dK + j][sK] = vrg0[j];
#pragma unroll
            for (int j = 0; j < 8; j++) Vs[nxt][dK + 8 + j][sK] = vrg1[j];
        }
    }

    // epilogue: normalize and store fp32
#pragma unroll
    for (int df = 0; df < 4; df++) {
#pragma unroll
        for (int r = 0; r < 4; r++) {
            int qrow = qbase + 16 * w + lg * 4 + r;
            out[(rowb + qrow) * 64 + 16 * df + l15] = oacc[df][r] / lrow[r];
        }
    }
}

extern "C" void kernel_launch(void* const* d_in, const int* in_sizes, int n_in,
                              void* d_out, int out_size, void* d_ws, size_t ws_size,
                              hipStream_t stream) {
    const float* x  = (const float*)d_in[0];
    const float* Wq = (const float*)d_in[1];
    const float* bq = (const float*)d_in[2];
    const float* Wk = (const float*)d_in[3];
    const float* bk = (const float*)d_in[4];
    const float* Wv = (const float*)d_in[5];
    const float* bv = (const float*)d_in[6];
    float* out = (float*)d_out;

    _Float16* ws = (_Float16*)d_ws;
    _Float16* wt = ws;                       // 3*64*768
    _Float16* qb = ws + 147456;              // 32768*64 each
    _Float16* kb = qb + 2097152;
    _Float16* vb = kb + 2097152;

    prep_w<<<576, 256, 0, stream>>>(Wq, Wk, Wv, wt);
    qkv_proj<<<512, 256, 0, stream>>>(x, wt, bq, bk, bv, qb, kb, vb);
    attn<<<512, 256, 0, stream>>>(qb, kb, vb, out);
}